// Round 7
// baseline (271.680 us; speedup 1.0000x reference)
//
#include <hip/hip_runtime.h>

#define NN 100000
#define NE 400000
#define F_IN 16
#define F_EDGE 8
#define EMB 16
#define NUM_GRAPHS 256

#define NPB 64                                   // nodes per gather block
#define GATHER_BLOCKS ((NN + NPB - 1) / NPB)     // 1563

#define SCAN_BD 1024
#define NSB ((NN + SCAN_BD - 1) / SCAN_BD)       // 98

// ---------------------------------------------------------------------------
// Workspace (ints/floats, 4B):
//   deg    [NN]      int   (zeroed)        edge histogram
//   rowptr [NN]      int                   exclusive scan of deg; fill turns it
//                                          into end-pointers (start = rowptr[n-1])
//   eid    [NE]      int                   edge ids bucketed by dst (CSR)
//   bsum   [128]     int                   scan block sums
//   gmax   [G*16]    u32   (zeroed)        pooled max (float bits, h>=0)
//   gsum   [G*16]    f32   (zeroed)
//   gcnt   [G]       f32   (zeroed)
// ---------------------------------------------------------------------------
#define DEG_F4   (NN / 4)          // 25000
#define POOL_F4  ((2 * NUM_GRAPHS * EMB + NUM_GRAPHS) / 4)   // 2112
#define ZERO_F4  (DEG_F4 + POOL_F4)                          // 27112

__global__ __launch_bounds__(256) void zero_kernel(float4* __restrict__ deg4,
                                                   float4* __restrict__ pool4)
{
    const int i = blockIdx.x * 256 + threadIdx.x;
    const float4 z = make_float4(0.f, 0.f, 0.f, 0.f);
    if (i < DEG_F4) deg4[i] = z;
    else if (i < ZERO_F4) pool4[i - DEG_F4] = z;
}

__global__ __launch_bounds__(256) void hist_kernel(const int* __restrict__ ei,
                                                   int* __restrict__ deg)
{
    const int e = blockIdx.x * 256 + threadIdx.x;
    if (e < NE) atomicAdd(&deg[ei[NE + e]], 1);
}

// Per-block Hillis-Steele exclusive scan of deg -> rowptr; block totals -> bsum.
__global__ __launch_bounds__(SCAN_BD) void scan_blocks(const int* __restrict__ deg,
                                                       int* __restrict__ rowptr,
                                                       int* __restrict__ bsum)
{
    __shared__ int sh[SCAN_BD];
    const int t = threadIdx.x;
    const int i = blockIdx.x * SCAN_BD + t;
    const int v = (i < NN) ? deg[i] : 0;
    sh[t] = v;
    __syncthreads();
    #pragma unroll
    for (int off = 1; off < SCAN_BD; off <<= 1) {
        const int add = (t >= off) ? sh[t - off] : 0;
        __syncthreads();
        sh[t] += add;
        __syncthreads();
    }
    if (i < NN) rowptr[i] = sh[t] - v;           // exclusive
    if (t == SCAN_BD - 1) bsum[blockIdx.x] = sh[t];
}

// Exclusive scan of the 98 block totals (single block).
__global__ __launch_bounds__(128) void scan_tops(int* __restrict__ bsum)
{
    __shared__ int sb[128];
    const int t = threadIdx.x;
    const int v = (t < NSB) ? bsum[t] : 0;
    sb[t] = v;
    __syncthreads();
    #pragma unroll
    for (int off = 1; off < 128; off <<= 1) {
        const int add = (t >= off) ? sb[t - off] : 0;
        __syncthreads();
        sb[t] += add;
        __syncthreads();
    }
    if (t < NSB) bsum[t] = sb[t] - v;            // exclusive
}

__global__ __launch_bounds__(SCAN_BD) void scan_add(int* __restrict__ rowptr,
                                                    const int* __restrict__ bsum)
{
    const int i = blockIdx.x * SCAN_BD + threadIdx.x;
    if (i < NN) rowptr[i] += bsum[blockIdx.x];
}

// Bucket edge ids by dst. After this, rowptr[n] = END of node n's range
// (start = rowptr[n-1], or 0 for n==0).
__global__ __launch_bounds__(256) void fill_kernel(const int* __restrict__ ei,
                                                   int* __restrict__ rowptr,
                                                   int* __restrict__ eid)
{
    const int e = blockIdx.x * 256 + threadIdx.x;
    if (e < NE) {
        const int dst = ei[NE + e];
        const int pos = atomicAdd(&rowptr[dst], 1);
        eid[pos] = e;
    }
}

// ---------------------------------------------------------------------------
// Fused gather + node + pooling. Block = 4 waves x 64 lanes; wave w owns nodes
// [n0+16w, n0+16w+16). One node at a time per wave -> UNIFORM control flow:
// lane (o = tid&15, q = (tid>>4)&3) holds W rows i = 4q..4q+3 in registers
// (zero LDS in the edge loop); quarter partials combine via 2x shfl_xor.
// h = relu(msg_mean + x@root^T + conv_b); per-block register-segmented pooled
// flush (few low-contention atomics). NO message-scatter atomics at all.
// ---------------------------------------------------------------------------
__global__ __launch_bounds__(256) void gather_node_kernel(
    const float* __restrict__ x, const int* __restrict__ ei,
    const float* __restrict__ ea, const float* __restrict__ nn1_w,
    const float* __restrict__ nn1_b, const int* __restrict__ batch,
    const float* __restrict__ root_w, const float* __restrict__ conv_b,
    const int* __restrict__ rowptr, const int* __restrict__ eid,
    unsigned int* __restrict__ gmax, float* __restrict__ gsum,
    float* __restrict__ gcnt)
{
    __shared__ float hsh[NPB * 16];
    __shared__ int   bsh[NPB];

    const int tid = threadIdx.x;
    const int o   = tid & 15;
    const int q   = (tid >> 4) & 3;
    const int w   = tid >> 6;
    const int n0  = blockIdx.x * NPB;

    // per-lane weight rows r = (4q+ii)*16 + o (one-time broadcast-ish loads)
    float4 w0[4], w1[4];
    float  bb[4];
    #pragma unroll
    for (int ii = 0; ii < 4; ii++) {
        const int r = (q * 4 + ii) * 16 + o;
        w0[ii] = *(const float4*)&nn1_w[r * 8];
        w1[ii] = *(const float4*)&nn1_w[r * 8 + 4];
        bb[ii] = nn1_b[r];
    }
    const float4 rw = *(const float4*)&root_w[o * 16 + q * 4];
    const float  cb = conv_b[o];

    if (tid < NPB) bsh[tid] = (n0 + tid < NN) ? batch[n0 + tid] : -1;

    for (int k = 0; k < 16; k++) {
        const int n = n0 + w * 16 + k;            // uniform across the wave
        if (n < NN) {
            const int st = (n > 0) ? rowptr[n - 1] : 0;
            const int en = rowptr[n];

            float acc = 0.f;
            for (int idx = st; idx < en; idx++) {
                const int ev  = eid[idx];
                const int src = ei[ev];
                const float4 a0 = *(const float4*)&ea[ev * 8];
                const float4 a1 = *(const float4*)&ea[ev * 8 + 4];
                const float4 xq = *(const float4*)&x[src * 16 + q * 4];
                const float xv[4] = {xq.x, xq.y, xq.z, xq.w};
                #pragma unroll
                for (int ii = 0; ii < 4; ii++) {
                    float u = bb[ii];
                    u = fmaf(a0.x, w0[ii].x, u); u = fmaf(a0.y, w0[ii].y, u);
                    u = fmaf(a0.z, w0[ii].z, u); u = fmaf(a0.w, w0[ii].w, u);
                    u = fmaf(a1.x, w1[ii].x, u); u = fmaf(a1.y, w1[ii].y, u);
                    u = fmaf(a1.z, w1[ii].z, u); u = fmaf(a1.w, w1[ii].w, u);
                    acc = fmaf(xv[ii], fmaxf(u, 0.f), acc);
                }
            }

            const float4 xn = *(const float4*)&x[n * 16 + q * 4];
            float ar = xn.x * rw.x + xn.y * rw.y + xn.z * rw.z + xn.w * rw.w;

            acc += __shfl_xor(acc, 16); acc += __shfl_xor(acc, 32);
            ar  += __shfl_xor(ar, 16);  ar  += __shfl_xor(ar, 32);

            const float deg = (float)(en - st);
            const float h = fmaxf(cb + ar + acc / fmaxf(deg, 1.f), 0.f);
            if (q == 0) hsh[(w * 16 + k) * 16 + o] = h;
        }
    }
    __syncthreads();

    if (tid < 16) {                // o = tid: segmented flush over NPB nodes
        int curg = bsh[0];
        float am = 0.f, as = 0.f, ac = 0.f;
        #pragma unroll 1
        for (int jj = 0; jj < NPB; jj++) {
            const int g = bsh[jj];
            if (g < 0) break;
            if (g != curg) {
                atomicMax(&gmax[curg * 16 + tid], __float_as_uint(am));
                atomicAdd(&gsum[curg * 16 + tid], as);
                if (tid == 0) atomicAdd(&gcnt[curg], ac);
                am = 0.f; as = 0.f; ac = 0.f; curg = g;
            }
            const float h = hsh[jj * 16 + tid];
            am = fmaxf(am, h); as += h; ac += 1.f;
        }
        atomicMax(&gmax[curg * 16 + tid], __float_as_uint(am));
        atomicAdd(&gsum[curg * 16 + tid], as);
        if (tid == 0) atomicAdd(&gcnt[curg], ac);
    }
}

// Head MLP: one thread per graph, single block.
__global__ __launch_bounds__(256) void head_kernel(
    const unsigned int* __restrict__ gmax, const float* __restrict__ gsum,
    const float* __restrict__ gcnt,
    const float* __restrict__ lin1_w, const float* __restrict__ lin1_b,
    const float* __restrict__ lin2_w, const float* __restrict__ lin2_b,
    float* __restrict__ out)
{
    const int g = threadIdx.x;

    float pooled[2 * EMB];
    #pragma unroll
    for (int o = 0; o < EMB; o++) pooled[o] = __uint_as_float(gmax[g * 16 + o]);
    const float c = fmaxf(gcnt[g], 1.f);
    #pragma unroll
    for (int o = 0; o < EMB; o++) pooled[EMB + o] = gsum[g * 16 + o] / c;

    float acc = lin2_b[0];
    #pragma unroll
    for (int k = 0; k < EMB; k++) {
        float a = lin1_b[k];
        #pragma unroll
        for (int cc = 0; cc < 2 * EMB; cc++)
            a = fmaf(pooled[cc], lin1_w[k * 32 + cc], a);
        acc = fmaf(fmaxf(a, 0.f), lin2_w[k], acc);
    }
    out[g] = acc;
}

extern "C" void kernel_launch(void* const* d_in, const int* in_sizes, int n_in,
                              void* d_out, int out_size, void* d_ws, size_t ws_size,
                              hipStream_t stream) {
    const float* x      = (const float*)d_in[0];
    const int*   ei     = (const int*)d_in[1];
    const float* ea     = (const float*)d_in[2];
    const int*   batch  = (const int*)d_in[3];
    const float* nn1_w  = (const float*)d_in[4];
    const float* nn1_b  = (const float*)d_in[5];
    const float* root_w = (const float*)d_in[6];
    const float* conv_b = (const float*)d_in[7];
    const float* lin1_w = (const float*)d_in[8];
    const float* lin1_b = (const float*)d_in[9];
    const float* lin2_w = (const float*)d_in[10];
    const float* lin2_b = (const float*)d_in[11];
    float* out = (float*)d_out;

    int*          deg    = (int*)d_ws;
    int*          rowptr = deg + NN;
    int*          eid    = rowptr + NN;
    int*          bsum   = eid + NE;
    unsigned int* gmax   = (unsigned int*)(bsum + 128);
    float*        gsum   = (float*)(gmax + NUM_GRAPHS * EMB);
    float*        gcnt   = gsum + NUM_GRAPHS * EMB;

    zero_kernel<<<(ZERO_F4 + 255) / 256, 256, 0, stream>>>(
        (float4*)deg, (float4*)gmax);
    hist_kernel<<<(NE + 255) / 256, 256, 0, stream>>>(ei, deg);
    scan_blocks<<<NSB, SCAN_BD, 0, stream>>>(deg, rowptr, bsum);
    scan_tops<<<1, 128, 0, stream>>>(bsum);
    scan_add<<<NSB, SCAN_BD, 0, stream>>>(rowptr, bsum);
    fill_kernel<<<(NE + 255) / 256, 256, 0, stream>>>(ei, rowptr, eid);
    gather_node_kernel<<<GATHER_BLOCKS, 256, 0, stream>>>(
        x, ei, ea, nn1_w, nn1_b, batch, root_w, conv_b, rowptr, eid,
        gmax, gsum, gcnt);
    head_kernel<<<1, 256, 0, stream>>>(gmax, gsum, gcnt,
                                       lin1_w, lin1_b, lin2_w, lin2_b, out);
}

// Round 8
// 170.326 us; speedup vs baseline: 1.5951x; 1.5951x over previous
//
#include <hip/hip_runtime.h>

#define NUM_NODES 100000
#define NUM_EDGES 400000
#define F_IN 16
#define F_EDGE 8
#define EMB 16
#define NUM_GRAPHS 256

#define EDGE_GRID 2048
#define NTILES (NUM_EDGES / 64)    // 6250 64-edge tiles

#define NPB 128                                        // nodes per node_kernel block
#define NODE_BLOCKS ((NUM_NODES + NPB - 1) / NPB)      // 782

// workspace floats to zero: sums + cnt + gmax + gsum + gcnt (contiguous)
#define WS_ZERO_FLOATS (NUM_NODES * EMB + NUM_NODES + 2 * NUM_GRAPHS * EMB + NUM_GRAPHS)

// ---------------------------------------------------------------------------
// Zero the accumulator workspace. WS_ZERO_FLOATS = 1,708,448, /4 exact.
// ---------------------------------------------------------------------------
__global__ __launch_bounds__(256) void zero_kernel(float4* __restrict__ ws)
{
    const int n4 = WS_ZERO_FLOATS / 4;
    const int stride = gridDim.x * 256;
    for (int i = blockIdx.x * 256 + threadIdx.x; i < n4; i += stride)
        ws[i] = make_float4(0.f, 0.f, 0.f, 0.f);
}

// ---------------------------------------------------------------------------
// Edge kernel — scatter structure, 4 edges/thread. The 32 weight
// ds_read_b128 per wave-iteration now serve 16 edges (2 KB LDS/edge, half of
// R6) -> per-CU LDS demand ~10-16 µs. Thread (eL=tid>>4, o=tid&15) handles
// contiguous edges 4eL..4eL+3 of the tile: int4 ei loads, 8 contiguous
// float4 ea loads. i-loop split in two halves of 8 to cap xr live range.
//   wtp row stride 12: slots 0-7 weights (bank 12o mod 32, 2-way = free),
//   slot 8 bias.
// ---------------------------------------------------------------------------
__global__ __launch_bounds__(256) void edge_kernel(
    const float* __restrict__ x, const int* __restrict__ ei,
    const float* __restrict__ ea, const float* __restrict__ nn1_w,
    const float* __restrict__ nn1_b, float* __restrict__ sums,
    float* __restrict__ cnt)
{
    __shared__ float wtp[256 * 12];   // row r=(i*16+o): 8 weights + bias + 3 pad

    const int tid = threadIdx.x;
    const int eL  = tid >> 4;
    const int o   = tid & 15;

    #pragma unroll
    for (int t = tid; t < F_IN * EMB * F_EDGE; t += 256)
        wtp[(t >> 3) * 12 + (t & 7)] = nn1_w[t];
    wtp[tid * 12 + 8] = nn1_b[tid];                    // row tid = i*16+o
    __syncthreads();                                   // the ONLY barrier

    float br[F_IN];
    #pragma unroll
    for (int i = 0; i < F_IN; i++) br[i] = wtp[(i * 16 + o) * 12 + 8];

    for (int t = blockIdx.x; t < NTILES; t += EDGE_GRID) {
        const int e0 = t * 64 + eL * 4;       // thread's 4 contiguous edges

        const int4 s4 = *(const int4*)&ei[e0];
        const int4 d4 = *(const int4*)&ei[NUM_EDGES + e0];
        const int src[4] = {s4.x, s4.y, s4.z, s4.w};
        const int dst[4] = {d4.x, d4.y, d4.z, d4.w};

        float4 A[8];                          // 4 edges x 8 attrs, contiguous
        #pragma unroll
        for (int r = 0; r < 8; r++) A[r] = *(const float4*)&ea[e0 * 8 + 4 * r];

        float acc[4] = {0.f, 0.f, 0.f, 0.f};

        #pragma unroll
        for (int h = 0; h < 2; h++) {         // halves of the i-dimension
            float4 xa[4], xb[4];
            #pragma unroll
            for (int e = 0; e < 4; e++) {
                xa[e] = *(const float4*)&x[src[e] * 16 + h * 8];
                xb[e] = *(const float4*)&x[src[e] * 16 + h * 8 + 4];
            }
            #pragma unroll
            for (int ii = 0; ii < 8; ii++) {
                const int i = h * 8 + ii;
                const float* wr = &wtp[(i * 16 + o) * 12];
                const float4 w0 = *(const float4*)wr;
                const float4 w1 = *(const float4*)(wr + 4);
                #pragma unroll
                for (int e = 0; e < 4; e++) {
                    const float4 a0 = A[2 * e];
                    const float4 a1 = A[2 * e + 1];
                    float u = br[i];
                    u = fmaf(a0.x, w0.x, u); u = fmaf(a0.y, w0.y, u);
                    u = fmaf(a0.z, w0.z, u); u = fmaf(a0.w, w0.w, u);
                    u = fmaf(a1.x, w1.x, u); u = fmaf(a1.y, w1.y, u);
                    u = fmaf(a1.z, w1.z, u); u = fmaf(a1.w, w1.w, u);
                    const float xv = (ii < 4)
                        ? ((ii == 0) ? xa[e].x : (ii == 1) ? xa[e].y
                                     : (ii == 2) ? xa[e].z : xa[e].w)
                        : ((ii == 4) ? xb[e].x : (ii == 5) ? xb[e].y
                                     : (ii == 6) ? xb[e].z : xb[e].w);
                    acc[e] = fmaf(xv, fmaxf(u, 0.f), acc[e]);
                }
            }
        }

        #pragma unroll
        for (int e = 0; e < 4; e++)
            atomicAdd(&sums[dst[e] * 16 + o], acc[e]);
        if (o == 0) {
            #pragma unroll
            for (int e = 0; e < 4; e++)
                atomicAdd(&cnt[dst[e]], 1.f);
        }
    }
}

// ---------------------------------------------------------------------------
// Node kernel (unchanged, absmax 0): one block per 128 nodes; h = relu(agg +
// x@root_w^T + conv_b); 16 flusher threads carry per-channel (max,sum,count)
// register accumulators, flushing atomics only on graph boundary / block end.
// ---------------------------------------------------------------------------
__global__ __launch_bounds__(256) void node_kernel(
    const float* __restrict__ x, const int* __restrict__ batch,
    const float* __restrict__ root_w, const float* __restrict__ conv_b,
    const float* __restrict__ sums, const float* __restrict__ cnt,
    unsigned int* __restrict__ gmax, float* __restrict__ gsum,
    float* __restrict__ gcnt)
{
    __shared__ float rwT[256];   // rwT[i*16+o] = root_w[o*16+i]
    __shared__ float xsh[256];
    __shared__ float ssh[256];
    __shared__ float csh[16];
    __shared__ int   bsh[16];
    __shared__ float hsh[256];

    const int tid = threadIdx.x;
    const int j   = tid >> 4;
    const int o   = tid & 15;
    const int n0  = blockIdx.x * NPB;

    rwT[(tid & 15) * 16 + (tid >> 4)] = root_w[tid];
    const float cb = conv_b[o];

    int   curg = batch[n0];
    float am = 0.f, asum = 0.f, ac = 0.f;

    for (int s0 = 0; s0 < NPB; s0 += 16) {
        const int base = n0 + s0;
        const int idx  = base * 16 + tid;
        const bool v   = (idx < NUM_NODES * 16);
        const float xv = v ? x[idx]    : 0.f;
        const float sv = v ? sums[idx] : 0.f;
        float cv = 1.f; int bv = -1;
        if (tid < 16) {
            const int n = base + tid;
            if (n < NUM_NODES) { cv = cnt[n]; bv = batch[n]; }
        }
        __syncthreads();   // prev sub-tile's hsh/bsh fully consumed
        xsh[tid] = xv; ssh[tid] = sv;
        if (tid < 16) { csh[tid] = cv; bsh[tid] = bv; }
        __syncthreads();

        float a = cb + ssh[j * 16 + o] / fmaxf(csh[j], 1.f);
        #pragma unroll
        for (int i = 0; i < F_IN; i++)
            a = fmaf(xsh[j * 16 + i], rwT[i * 16 + o], a);
        hsh[tid] = fmaxf(a, 0.f);
        __syncthreads();   // hsh ready

        if (tid < 16) {
            #pragma unroll 1
            for (int jj = 0; jj < 16; jj++) {
                const int g = bsh[jj];
                if (g < 0) break;
                if (g != curg) {
                    atomicMax(&gmax[curg * 16 + o], __float_as_uint(am));
                    atomicAdd(&gsum[curg * 16 + o], asum);
                    if (o == 0) atomicAdd(&gcnt[curg], ac);
                    am = 0.f; asum = 0.f; ac = 0.f; curg = g;
                }
                const float h = hsh[jj * 16 + o];
                am = fmaxf(am, h); asum += h; ac += 1.f;
            }
        }
    }

    if (tid < 16) {
        atomicMax(&gmax[curg * 16 + o], __float_as_uint(am));
        atomicAdd(&gsum[curg * 16 + o], asum);
        if (o == 0) atomicAdd(&gcnt[curg], ac);
    }
}

// Head MLP: one thread per graph, single block.
__global__ __launch_bounds__(256) void head_kernel(
    const unsigned int* __restrict__ gmax, const float* __restrict__ gsum,
    const float* __restrict__ gcnt,
    const float* __restrict__ lin1_w, const float* __restrict__ lin1_b,
    const float* __restrict__ lin2_w, const float* __restrict__ lin2_b,
    float* __restrict__ out)
{
    const int g = threadIdx.x;

    float pooled[2 * EMB];
    #pragma unroll
    for (int o = 0; o < EMB; o++) pooled[o] = __uint_as_float(gmax[g * 16 + o]);
    const float c = fmaxf(gcnt[g], 1.f);
    #pragma unroll
    for (int o = 0; o < EMB; o++) pooled[EMB + o] = gsum[g * 16 + o] / c;

    float acc = lin2_b[0];
    #pragma unroll
    for (int k = 0; k < EMB; k++) {
        float a = lin1_b[k];
        #pragma unroll
        for (int cc = 0; cc < 2 * EMB; cc++)
            a = fmaf(pooled[cc], lin1_w[k * 32 + cc], a);
        acc = fmaf(fmaxf(a, 0.f), lin2_w[k], acc);
    }
    out[g] = acc;
}

extern "C" void kernel_launch(void* const* d_in, const int* in_sizes, int n_in,
                              void* d_out, int out_size, void* d_ws, size_t ws_size,
                              hipStream_t stream) {
    const float* x      = (const float*)d_in[0];
    const int*   ei     = (const int*)d_in[1];
    const float* ea     = (const float*)d_in[2];
    const int*   batch  = (const int*)d_in[3];
    const float* nn1_w  = (const float*)d_in[4];
    const float* nn1_b  = (const float*)d_in[5];
    const float* root_w = (const float*)d_in[6];
    const float* conv_b = (const float*)d_in[7];
    const float* lin1_w = (const float*)d_in[8];
    const float* lin1_b = (const float*)d_in[9];
    const float* lin2_w = (const float*)d_in[10];
    const float* lin2_b = (const float*)d_in[11];
    float* out = (float*)d_out;

    float*        sums = (float*)d_ws;
    float*        cnt  = sums + (size_t)NUM_NODES * EMB;
    unsigned int* gmax = (unsigned int*)(cnt + NUM_NODES);
    float*        gsum = (float*)(gmax + NUM_GRAPHS * EMB);
    float*        gcnt = gsum + NUM_GRAPHS * EMB;

    zero_kernel<<<1024, 256, 0, stream>>>((float4*)d_ws);
    edge_kernel<<<EDGE_GRID, 256, 0, stream>>>(x, ei, ea, nn1_w, nn1_b, sums, cnt);
    node_kernel<<<NODE_BLOCKS, 256, 0, stream>>>(
        x, batch, root_w, conv_b, sums, cnt, gmax, gsum, gcnt);
    head_kernel<<<1, 256, 0, stream>>>(gmax, gsum, gcnt,
                                       lin1_w, lin1_b, lin2_w, lin2_b, out);
}